// Round 2
// baseline (124.418 us; speedup 1.0000x reference)
//
#include <hip/hip_runtime.h>

// GNNEmbeds: 3-layer NNConv, scalar edge features.
// W(e) = attr_e*A + B  =>  msg_e = attr_e*(h[src]@A) + (h[src]@B)
// Layer l out: h_l = hin@root + bias + sum_edges ( attr*(hin[src]@A) + hin[src]@B )
//
// Gather formulation (no global atomics): kernel for layer l+1 owns a TR-row dst
// tile; it reconstructs hin = relu(R_l + sum over edges with dst in tile of
// attr*U_l[src] + V_l[src]) in LDS, then runs the three GEMMs (A,B,root) of
// layer l+1 producing U_{l+1}, V_{l+1}, R_{l+1} with plain stores.
// Layer 1 (in_c=2) U/V are 2 FMAs/elem, computed on the fly from x.

#define HD 128
#define TR 16      // dst rows per tile
#define CH 2048    // edge-scan chunk (LDS list bound, safe for any distribution)

struct GatherLists {
    float hs[TR][HD];
    int   erow[CH];
    int   esrc[CH];
    float eattr[CH];
    int   cnt;
};

// ---- GEMM body: out{U,V,R}[tile] = hs @ {A,B,root} (+bias for R) ----
__device__ __forceinline__ void gemm_from_lds(
    const float hs[TR][HD], int n0, int t, int y,
    const float* __restrict__ lw, const float* __restrict__ lb,
    const float* __restrict__ root, const float* __restrict__ bias,
    float* __restrict__ U, float* __restrict__ V, float* __restrict__ R)
{
    const float* W; float* O;
    if      (y == 0) { W = lw;   O = U; }
    else if (y == 1) { W = lb;   O = V; }
    else             { W = root; O = R; }

    const int colg = (t & 31) << 2;   // 4 contiguous cols
    const int rowg = (t >> 5) << 1;   // 2 rows (8 wave-groups x 2 = 16)

    float acc[2][4];
#pragma unroll
    for (int r = 0; r < 2; ++r)
#pragma unroll
        for (int c = 0; c < 4; ++c) acc[r][c] = 0.f;

#pragma unroll 8
    for (int k = 0; k < HD; ++k) {
        const float4 w = *(const float4*)(W + k * HD + colg);
        const float h0 = hs[rowg + 0][k];   // broadcast within wave: free
        const float h1 = hs[rowg + 1][k];
        acc[0][0] = fmaf(h0, w.x, acc[0][0]); acc[0][1] = fmaf(h0, w.y, acc[0][1]);
        acc[0][2] = fmaf(h0, w.z, acc[0][2]); acc[0][3] = fmaf(h0, w.w, acc[0][3]);
        acc[1][0] = fmaf(h1, w.x, acc[1][0]); acc[1][1] = fmaf(h1, w.y, acc[1][1]);
        acc[1][2] = fmaf(h1, w.z, acc[1][2]); acc[1][3] = fmaf(h1, w.w, acc[1][3]);
    }

    float4 b = make_float4(0.f, 0.f, 0.f, 0.f);
    if (y == 2) b = *(const float4*)(bias + colg);
#pragma unroll
    for (int r = 0; r < 2; ++r) {
        float4 o;
        o.x = acc[r][0] + b.x; o.y = acc[r][1] + b.y;
        o.z = acc[r][2] + b.z; o.w = acc[r][3] + b.w;
        *(float4*)(O + (size_t)(n0 + rowg + r) * HD + colg) = o;
    }
}

// ---- K_A: layer-1 gather (from x, in_c=2) + layer-2 GEMMs ----
__global__ __launch_bounds__(256) void kA(
    const float* __restrict__ x, const int* __restrict__ ei,
    const float* __restrict__ attr,
    const float* __restrict__ lw1, const float* __restrict__ lb1,
    const float* __restrict__ root1, const float* __restrict__ bias1,
    const float* __restrict__ lw2, const float* __restrict__ lb2,
    const float* __restrict__ root2, const float* __restrict__ bias2,
    float* __restrict__ U2, float* __restrict__ V2, float* __restrict__ R2,
    int E)
{
    __shared__ GatherLists g;
    const int t = threadIdx.x;
    const int n0 = blockIdx.x * TR;

    // hin init: root-term of layer 1 = x @ root1 + bias1
    for (int i = t; i < TR * HD; i += 256) {
        const int r = i >> 7, c = i & 127;
        const float x0 = x[(n0 + r) * 2 + 0];
        const float x1 = x[(n0 + r) * 2 + 1];
        g.hs[r][c] = fmaf(x0, root1[c], fmaf(x1, root1[HD + c], bias1[c]));
    }
    __syncthreads();

    // gather: hs[d-n0] += attr*(x[s]@A1) + (x[s]@B1)
    for (int base = 0; base < E; base += CH) {
        if (t == 0) g.cnt = 0;
        __syncthreads();
        const int hi = (base + CH < E) ? base + CH : E;
        for (int e = base + t; e < hi; e += 256) {
            const int d = ei[E + e];
            const unsigned r = (unsigned)(d - n0);
            if (r < TR) {
                const int idx = atomicAdd(&g.cnt, 1);
                g.erow[idx] = r; g.esrc[idx] = ei[e]; g.eattr[idx] = attr[e];
            }
        }
        __syncthreads();
        const int tot = g.cnt * 32;
        for (int i = t; i < tot; i += 256) {
            const int li = i >> 5, c = (i & 31) << 2;
            const int r = g.erow[li], s = g.esrc[li];
            const float a = g.eattr[li];
            const float x0 = x[s * 2 + 0], x1 = x[s * 2 + 1];
            const float4 a0 = *(const float4*)(lw1 + c);
            const float4 a1 = *(const float4*)(lw1 + HD + c);
            const float4 b0 = *(const float4*)(lb1 + c);
            const float4 b1 = *(const float4*)(lb1 + HD + c);
            atomicAdd(&g.hs[r][c + 0], fmaf(a, fmaf(x0, a0.x, x1 * a1.x), fmaf(x0, b0.x, x1 * b1.x)));
            atomicAdd(&g.hs[r][c + 1], fmaf(a, fmaf(x0, a0.y, x1 * a1.y), fmaf(x0, b0.y, x1 * b1.y)));
            atomicAdd(&g.hs[r][c + 2], fmaf(a, fmaf(x0, a0.z, x1 * a1.z), fmaf(x0, b0.z, x1 * b1.z)));
            atomicAdd(&g.hs[r][c + 3], fmaf(a, fmaf(x0, a0.w, x1 * a1.w), fmaf(x0, b0.w, x1 * b1.w)));
        }
        __syncthreads();
    }

    // relu
    for (int i = t; i < TR * HD; i += 256)
        (&g.hs[0][0])[i] = fmaxf((&g.hs[0][0])[i], 0.f);
    __syncthreads();

    gemm_from_lds(g.hs, n0, t, blockIdx.y, lw2, lb2, root2, bias2, U2, V2, R2);
}

// ---- K_B: layer-2 gather (from U2,V2,R2) + layer-3 GEMMs ----
__global__ __launch_bounds__(256) void kB(
    const int* __restrict__ ei, const float* __restrict__ attr,
    const float* __restrict__ U2, const float* __restrict__ V2,
    const float* __restrict__ R2,
    const float* __restrict__ lw3, const float* __restrict__ lb3,
    const float* __restrict__ root3, const float* __restrict__ bias3,
    float* __restrict__ U3, float* __restrict__ V3, float* __restrict__ R3,
    int E)
{
    __shared__ GatherLists g;
    const int t = threadIdx.x;
    const int n0 = blockIdx.x * TR;

    for (int i = t; i < TR * HD / 4; i += 256)
        ((float4*)&g.hs[0][0])[i] = ((const float4*)(R2 + (size_t)n0 * HD))[i];
    __syncthreads();

    for (int base = 0; base < E; base += CH) {
        if (t == 0) g.cnt = 0;
        __syncthreads();
        const int hi = (base + CH < E) ? base + CH : E;
        for (int e = base + t; e < hi; e += 256) {
            const int d = ei[E + e];
            const unsigned r = (unsigned)(d - n0);
            if (r < TR) {
                const int idx = atomicAdd(&g.cnt, 1);
                g.erow[idx] = r; g.esrc[idx] = ei[e]; g.eattr[idx] = attr[e];
            }
        }
        __syncthreads();
        const int tot = g.cnt * 32;
        for (int i = t; i < tot; i += 256) {
            const int li = i >> 5, c = (i & 31) << 2;
            const int r = g.erow[li], s = g.esrc[li];
            const float a = g.eattr[li];
            const float4 u = *(const float4*)(U2 + (size_t)s * HD + c);
            const float4 v = *(const float4*)(V2 + (size_t)s * HD + c);
            atomicAdd(&g.hs[r][c + 0], fmaf(a, u.x, v.x));
            atomicAdd(&g.hs[r][c + 1], fmaf(a, u.y, v.y));
            atomicAdd(&g.hs[r][c + 2], fmaf(a, u.z, v.z));
            atomicAdd(&g.hs[r][c + 3], fmaf(a, u.w, v.w));
        }
        __syncthreads();
    }

    for (int i = t; i < TR * HD; i += 256)
        (&g.hs[0][0])[i] = fmaxf((&g.hs[0][0])[i], 0.f);
    __syncthreads();

    gemm_from_lds(g.hs, n0, t, blockIdx.y, lw3, lb3, root3, bias3, U3, V3, R3);
}

// ---- K_C: layer-3 gather -> out (no relu) ----
__global__ __launch_bounds__(256) void kC(
    const int* __restrict__ ei, const float* __restrict__ attr,
    const float* __restrict__ U3, const float* __restrict__ V3,
    const float* __restrict__ R3, float* __restrict__ out, int E)
{
    __shared__ GatherLists g;
    const int t = threadIdx.x;
    const int n0 = blockIdx.x * TR;

    for (int i = t; i < TR * HD / 4; i += 256)
        ((float4*)&g.hs[0][0])[i] = ((const float4*)(R3 + (size_t)n0 * HD))[i];
    __syncthreads();

    for (int base = 0; base < E; base += CH) {
        if (t == 0) g.cnt = 0;
        __syncthreads();
        const int hi = (base + CH < E) ? base + CH : E;
        for (int e = base + t; e < hi; e += 256) {
            const int d = ei[E + e];
            const unsigned r = (unsigned)(d - n0);
            if (r < TR) {
                const int idx = atomicAdd(&g.cnt, 1);
                g.erow[idx] = r; g.esrc[idx] = ei[e]; g.eattr[idx] = attr[e];
            }
        }
        __syncthreads();
        const int tot = g.cnt * 32;
        for (int i = t; i < tot; i += 256) {
            const int li = i >> 5, c = (i & 31) << 2;
            const int r = g.erow[li], s = g.esrc[li];
            const float a = g.eattr[li];
            const float4 u = *(const float4*)(U3 + (size_t)s * HD + c);
            const float4 v = *(const float4*)(V3 + (size_t)s * HD + c);
            atomicAdd(&g.hs[r][c + 0], fmaf(a, u.x, v.x));
            atomicAdd(&g.hs[r][c + 1], fmaf(a, u.y, v.y));
            atomicAdd(&g.hs[r][c + 2], fmaf(a, u.z, v.z));
            atomicAdd(&g.hs[r][c + 3], fmaf(a, u.w, v.w));
        }
        __syncthreads();
    }

    for (int i = t; i < TR * HD / 4; i += 256)
        ((float4*)(out + (size_t)n0 * HD))[i] = ((const float4*)&g.hs[0][0])[i];
}

extern "C" void kernel_launch(void* const* d_in, const int* in_sizes, int n_in,
                              void* d_out, int out_size, void* d_ws, size_t ws_size,
                              hipStream_t stream) {
    const float* x     = (const float*)d_in[0];
    const int*   ei    = (const int*)  d_in[1];
    const float* attr  = (const float*)d_in[2];
    const float* lw1   = (const float*)d_in[3];
    const float* lb1   = (const float*)d_in[4];
    const float* root1 = (const float*)d_in[5];
    const float* bias1 = (const float*)d_in[6];
    const float* lw2   = (const float*)d_in[7];
    const float* lb2   = (const float*)d_in[8];
    const float* root2 = (const float*)d_in[9];
    const float* bias2 = (const float*)d_in[10];
    const float* lw3   = (const float*)d_in[11];
    const float* lb3   = (const float*)d_in[12];
    const float* root3 = (const float*)d_in[13];
    const float* bias3 = (const float*)d_in[14];

    const int N = in_sizes[0] / 2;   // x: [N,2]
    const int E = in_sizes[1] / 2;   // edge_index: [2,E]

    float* out = (float*)d_out;
    float* ws  = (float*)d_ws;
    float* U2 = ws + 0 * (size_t)N * HD;
    float* V2 = ws + 1 * (size_t)N * HD;
    float* R2 = ws + 2 * (size_t)N * HD;
    float* U3 = ws + 3 * (size_t)N * HD;
    float* V3 = ws + 4 * (size_t)N * HD;
    float* R3 = ws + 5 * (size_t)N * HD;

    const dim3 gAB(N / TR, 3);
    kA<<<gAB, 256, 0, stream>>>(x, ei, attr, lw1, lb1, root1, bias1,
                                lw2, lb2, root2, bias2, U2, V2, R2, E);
    kB<<<gAB, 256, 0, stream>>>(ei, attr, U2, V2, R2,
                                lw3, lb3, root3, bias3, U3, V3, R3, E);
    kC<<<dim3(N / TR), 256, 0, stream>>>(ei, attr, U3, V3, R3, out, E);
}